// Round 6
// baseline (2473.034 us; speedup 1.0000x reference)
//
#include <hip/hip_runtime.h>
#include <math.h>

#define NEGV (-100000.0f)
constexpr int Bn = 64, Sn = 512, En = 256, Hn = 256, HIDn = 512, Tn = 9;
constexpr int START_T = Tn - 2, STOP_T = Tn - 1;
constexpr int Mn = Bn * Sn; // 32768 rows

typedef unsigned int u32;
typedef unsigned short u16;
typedef unsigned long long u64;
typedef short short8 __attribute__((ext_vector_type(8)));
typedef float f32x4 __attribute__((ext_vector_type(4)));
typedef int i32x4 __attribute__((ext_vector_type(4)));

__device__ __forceinline__ float sigf(float x) { return 1.0f / (1.0f + __expf(-x)); }
__device__ __forceinline__ float tanh_f(float x) { return 2.0f / (1.0f + __expf(-2.0f * x)) - 1.0f; }
__device__ __forceinline__ u16 f2bf(float f) {
  u32 u = __float_as_uint(f);
  return (u16)((u + 0x7fffu + ((u >> 16) & 1u)) >> 16);
}
__device__ __forceinline__ float bflo(u32 u) { return __uint_as_float(u << 16); }
__device__ __forceinline__ float bfhi(u32 u) { return __uint_as_float(u & 0xffff0000u); }
__device__ __forceinline__ float b2f(u16 v) { return __uint_as_float((u32)v << 16); }

// LDS-only workgroup barrier: does NOT drain vmcnt (global loads/stores stay in flight).
// Correct here because the barrier only orders LDS traffic; rule #18 fences included.
__device__ __forceinline__ void bar_lds() {
  __builtin_amdgcn_sched_barrier(0);
  asm volatile("s_waitcnt lgkmcnt(0)" ::: "memory");
  __builtin_amdgcn_s_barrier();
  __builtin_amdgcn_sched_barrier(0);
}

// ---------------- scales for int8 recurrent weights: per gate-row ----------------
__global__ void prep_scales(const float* __restrict__ whh0, const float* __restrict__ whh1,
                            float* __restrict__ sw0, float* __restrict__ dqs0,
                            float* __restrict__ sw1, float* __restrict__ dqs1) {
  int r = blockIdx.x * blockDim.x + threadIdx.x;
  if (r >= 2048) return;
  const float* p0 = whh0 + (size_t)r * 256;
  const float* p1 = whh1 + (size_t)r * 256;
  float m0 = 0.f, m1 = 0.f;
  for (int k = 0; k < 256; ++k) {
    m0 = fmaxf(m0, fabsf(p0[k]));
    m1 = fmaxf(m1, fabsf(p1[k]));
  }
  m0 = fmaxf(m0, 1e-8f); m1 = fmaxf(m1, 1e-8f);
  sw0[r] = m0 / 127.f; dqs0[r] = m0 / (127.f * 127.f);
  sw1[r] = m1 / 127.f; dqs1[r] = m1 / (127.f * 127.f);
}

// ---------------- prep: wih -> bf16 MFMA B-frags; whh -> int8 MFMA B-frags ----------------
// whh i8 frags: wq[d][w(8)][q(8)][kt(4)][lane(64)][j(16)];
//   n=(q*8+w)*16+(lane&15); k=kt*64+((lane>>4)&3)*16+j
// wih frags (gemm): wifrag[d][nb][w][ks][lane][j]; n=nb*64+w*16+(lane&15); k=ks*32+((lane>>4)&3)*8+j
__global__ void prep_kernel(const float* __restrict__ wih0, const float* __restrict__ whh0,
                            const float* __restrict__ bih0, const float* __restrict__ bhh0,
                            const float* __restrict__ wih1, const float* __restrict__ whh1,
                            const float* __restrict__ bih1, const float* __restrict__ bhh1,
                            u16* __restrict__ wifrag0, u16* __restrict__ wifrag1,
                            char* __restrict__ wq0, char* __restrict__ wq1,
                            const float* __restrict__ sw0, const float* __restrict__ sw1,
                            float* __restrict__ bias0, float* __restrict__ bias1) {
  int tid = blockIdx.x * blockDim.x + threadIdx.x;
  int nth = gridDim.x * blockDim.x;
  // wih0 frags: K=256, KS=8 -> 2*16*4*8*64*8 = 524288 u16
  for (int idx = tid; idx < 524288; idx += nth) {
    int j = idx & 7, lane = (idx >> 3) & 63, ks = (idx >> 9) & 7,
        w2 = (idx >> 12) & 3, nb = (idx >> 14) & 15, d = (idx >> 18) & 1;
    int n = nb * 64 + w2 * 16 + (lane & 15);
    int k = ks * 32 + ((lane >> 4) & 3) * 8 + j;
    wifrag0[idx] = f2bf(wih0[(d * 1024 + n) * 256 + k]);
  }
  // wih1 frags: K=512, KS=16 -> 2*16*4*16*64*8 = 1048576 u16
  for (int idx = tid; idx < 1048576; idx += nth) {
    int j = idx & 7, lane = (idx >> 3) & 63, ks = (idx >> 9) & 15,
        w2 = (idx >> 13) & 3, nb = (idx >> 15) & 15, d = (idx >> 19) & 1;
    int n = nb * 64 + w2 * 16 + (lane & 15);
    int k = ks * 32 + ((lane >> 4) & 3) * 8 + j;
    wifrag1[idx] = f2bf(wih1[(d * 1024 + n) * 512 + k]);
  }
  // whh int8 frags: [d][w][q][kt][lane][j] -> 524288 bytes per layer
  for (int idx = tid; idx < 524288; idx += nth) {
    int j = idx & 15, lane = (idx >> 4) & 63, kt = (idx >> 10) & 3,
        q = (idx >> 12) & 7, wv = (idx >> 15) & 7, d = (idx >> 18) & 1;
    int nt = q * 8 + wv;
    int n = nt * 16 + (lane & 15);
    int k = kt * 64 + ((lane >> 4) & 3) * 16 + j;
    int row = d * 1024 + n;
    float v0 = whh0[(size_t)row * 256 + k] / sw0[row];
    float v1 = whh1[(size_t)row * 256 + k] / sw1[row];
    wq0[idx] = (char)(int)fminf(fmaxf(rintf(v0), -127.f), 127.f);
    wq1[idx] = (char)(int)fminf(fmaxf(rintf(v1), -127.f), 127.f);
  }
  for (int idx = tid; idx < 2 * 1024; idx += nth) {
    bias0[idx] = bih0[idx] + bhh0[idx];
    bias1[idx] = bih1[idx] + bhh1[idx];
  }
}

// ---------------- MFMA input-projection GEMM -> gate-packed gx2[dir][m][unit][gate] ----------------
template <int KS, bool GATHER>   // KS = K/32
__global__ __launch_bounds__(256) void gemm_ih(
    const void* __restrict__ xsrc_v,   // GATHER: fp32 emb; else bf16 rows [M][512]
    const int* __restrict__ sent,
    const uint4* __restrict__ wifrag,  // [2][16][4][KS][64] uint4
    const float* __restrict__ bias,    // [2][1024]
    u16* __restrict__ gx2)             // [2*M][256][4] bf16
{
  constexpr int K = KS * 32;
  constexpr int PITCH = K + 8;
  __shared__ u16 As[64][PITCH];
  const int tid = threadIdx.x;
  const int l = tid & 63;
  const int w = tid >> 6;
  const int col = l & 15;
  const int quad = (l >> 4) & 3;
  const int m0 = blockIdx.x * 64;
  const int dir = blockIdx.y;

  {
    const int lr = tid >> 2, lq = tid & 3;
    if constexpr (GATHER) {
      const float4* xrow = reinterpret_cast<const float4*>(
          (const float*)xsrc_v + (size_t)sent[m0 + lr] * 256) + lq * 16;
      u32* dst = reinterpret_cast<u32*>(&As[lr][lq * 64]);
#pragma unroll
      for (int i = 0; i < 16; ++i) {
        float4 v = xrow[i];
        dst[i * 2 + 0] = (u32)f2bf(v.x) | ((u32)f2bf(v.y) << 16);
        dst[i * 2 + 1] = (u32)f2bf(v.z) | ((u32)f2bf(v.w) << 16);
      }
    } else {
      const uint4* xrow = reinterpret_cast<const uint4*>(
          (const u16*)xsrc_v + (size_t)(m0 + lr) * 512) + lq * 16;
      uint4* dst = reinterpret_cast<uint4*>(&As[lr][lq * 128]);
#pragma unroll
      for (int i = 0; i < 16; ++i) dst[i] = xrow[i];
    }
  }
  __syncthreads();

  const uint4* wfd = wifrag + (size_t)dir * 16 * 4 * KS * 64;
#pragma unroll 1
  for (int nb = 0; nb < 16; ++nb) {
    uint4 bf[KS];
#pragma unroll
    for (int ks = 0; ks < KS; ++ks)
      bf[ks] = wfd[((nb * 4 + w) * KS + ks) * 64 + l];

    f32x4 acc[4];
#pragma unroll
    for (int mt = 0; mt < 4; ++mt) acc[mt] = (f32x4){0.f, 0.f, 0.f, 0.f};
#pragma unroll
    for (int ks = 0; ks < KS; ++ks) {
      short8 b8 = __builtin_bit_cast(short8, bf[ks]);
#pragma unroll
      for (int mt = 0; mt < 4; ++mt) {
        uint4 av = *reinterpret_cast<const uint4*>(&As[mt * 16 + col][ks * 32 + quad * 8]);
        acc[mt] = __builtin_amdgcn_mfma_f32_16x16x32_bf16(
            __builtin_bit_cast(short8, av), b8, acc[mt], 0, 0, 0);
      }
    }

    const int n = nb * 64 + w * 16 + col;
    const int gate = n >> 8, unit = n & 255;
    const float bv = bias[dir * 1024 + n];
#pragma unroll
    for (int mt = 0; mt < 4; ++mt) {
#pragma unroll
      for (int r = 0; r < 4; ++r) {
        int m = m0 + mt * 16 + quad * 4 + r;
        gx2[((size_t)(dir * Mn + m) * 256 + unit) * 4 + gate] = f2bf(acc[mt][r] + bv);
      }
    }
  }
}

// ---------------- MFMA recurrence v11: v10 + LDS-only barriers (no vmcnt drain per step) ----
// Grid: 32 blocks = (dir 2) x (4-row group 16). Block: 512 thr = 8 waves, 2 waves/SIMD.
// Wave w holds n-tiles q*8+w (q=0..7) of Whh in registers (bw[8][4] i32x4 = 128 regs).
// Per step: ds_read A -> 32 MFMA -> quad0 scatter raw i32 acc to LDS -> lgkm-BAR ->
//   512 lanes: 2 units x 1 row: dequant + nonlin + h writes -> lgkm-BAR.
// gx load and out store remain in flight across barriers (consumed via compiler vmcnt waits).
__global__ __launch_bounds__(512, 2) void lstm_recur_v11(
    const i32x4* __restrict__ wq,     // [2][8][8][4][64] i32x4
    const float* __restrict__ dqs,    // [2][1024]
    const u16* __restrict__ gx2,      // [2*Mn][256][4] bf16
    u16* __restrict__ out)            // [B][S][512] bf16
{
  __shared__ char Ah8[2][4][288];     // dbuf int8 h tile [4 rows][256 units], pitch 288
  __shared__ int accL[4][1028];       // raw i32 acc [row][unit*4+gate], pitch 1028 dwords
  const int tid = threadIdx.x;
  const int l = tid & 63;
  const int w = tid >> 6;             // wave 0..7
  const int col = l & 15;
  const int quad = (l >> 4) & 3;
  const int dir = blockIdx.x >> 4;
  const int bq = blockIdx.x & 15;

  // epilogue assignment: lane tid -> (row erow, units u0, u0+1)
  const int erow = tid & 3;
  const int u0 = (tid >> 2) * 2;

  // ---- int8 recurrent weights into registers: 32 x i32x4 per lane ----
  i32x4 bw[8][4];
  {
    const i32x4* wp = wq + ((size_t)dir * 8 + w) * 8 * 4 * 64;
#pragma unroll
    for (int q = 0; q < 8; ++q)
#pragma unroll
      for (int kt = 0; kt < 4; ++kt)
        bw[q][kt] = wp[(q * 4 + kt) * 64 + l];
  }

  // dequant scales for this lane's two units (row = g*256+unit)
  float sc[2][4];
#pragma unroll
  for (int du = 0; du < 2; ++du)
#pragma unroll
    for (int g = 0; g < 4; ++g)
      sc[du][g] = dqs[dir * 1024 + g * 256 + u0 + du];

  const int mrow = bq * 4 + erow;
  const uint4* gp = reinterpret_cast<const uint4*>(gx2) +
                    (size_t)(dir * Mn + mrow * Sn) * 128 + (u0 >> 1);
  u32* op = reinterpret_cast<u32*>(out + (size_t)mrow * Sn * HIDn + dir * Hn + u0);

  float c0 = 0.f, c1 = 0.f;

  for (int s = 0; s < Sn; ++s) {
    const int t = dir ? (Sn - 1 - s) : s;
    uint4 g4 = gp[(size_t)t * 128];   // stays in flight across the lgkm-only barrier

    if (s > 0) {
      i32x4 av[4];
#pragma unroll
      for (int kt = 0; kt < 4; ++kt)
        av[kt] = *reinterpret_cast<const i32x4*>(
            &Ah8[(s + 1) & 1][col & 3][kt * 64 + quad * 16]);
      i32x4 acc[8];
#pragma unroll
      for (int q = 0; q < 8; ++q) acc[q] = (i32x4){0, 0, 0, 0};
#pragma unroll
      for (int kt = 0; kt < 4; ++kt)
#pragma unroll
        for (int q = 0; q < 8; ++q)
          acc[q] = __builtin_amdgcn_mfma_i32_16x16x64_i8(av[kt], bw[q][kt], acc[q], 0, 0, 0);
      if (quad == 0) {
        // rows 0..3 of C are the real batch rows; scatter raw i32 to LDS
#pragma unroll
        for (int e = 0; e < 2; ++e)
#pragma unroll
          for (int r = 0; r < 4; ++r) {
            i32x4 v = (i32x4){acc[0 + e][r], acc[2 + e][r], acc[4 + e][r], acc[6 + e][r]};
            *reinterpret_cast<i32x4*>(&accL[r][(e * 128 + w * 16 + col) * 4]) = v;
          }
      }
    }
    bar_lds();   // BAR1: accL ready (lgkm only; g4 load still in flight)

    float a00 = 0.f, a01 = 0.f, a02 = 0.f, a03 = 0.f;
    float a10 = 0.f, a11 = 0.f, a12 = 0.f, a13 = 0.f;
    if (s > 0) {
      i32x4 q0 = *reinterpret_cast<const i32x4*>(&accL[erow][u0 * 4]);
      i32x4 q1 = *reinterpret_cast<const i32x4*>(&accL[erow][u0 * 4 + 4]);
      a00 = (float)q0[0] * sc[0][0]; a01 = (float)q0[1] * sc[0][1];
      a02 = (float)q0[2] * sc[0][2]; a03 = (float)q0[3] * sc[0][3];
      a10 = (float)q1[0] * sc[1][0]; a11 = (float)q1[1] * sc[1][1];
      a12 = (float)q1[2] * sc[1][2]; a13 = (float)q1[3] * sc[1][3];
    }
    float gi0 = a00 + b2f((u16)(g4.x & 0xffff));
    float gf0 = a01 + b2f((u16)(g4.x >> 16));
    float gg0 = a02 + b2f((u16)(g4.y & 0xffff));
    float go0 = a03 + b2f((u16)(g4.y >> 16));
    float gi1 = a10 + b2f((u16)(g4.z & 0xffff));
    float gf1 = a11 + b2f((u16)(g4.z >> 16));
    float gg1 = a12 + b2f((u16)(g4.w & 0xffff));
    float go1 = a13 + b2f((u16)(g4.w >> 16));

    c0 = sigf(gf0) * c0 + sigf(gi0) * tanh_f(gg0);
    float h0 = sigf(go0) * tanh_f(c0);
    c1 = sigf(gf1) * c1 + sigf(gi1) * tanh_f(gg1);
    float h1 = sigf(go1) * tanh_f(c1);

    // LDS write first (shortens the lgkm wait at the barrier), then fire-and-forget store
    int qi0 = (int)rintf(h0 * 127.f);
    int qi1 = (int)rintf(h1 * 127.f);
    u16 hq = (u16)((qi0 & 0xff) | ((qi1 & 0xff) << 8));
    *reinterpret_cast<u16*>(&Ah8[s & 1][erow][u0]) = hq;
    op[(size_t)t * 256] = (u32)f2bf(h0) | ((u32)f2bf(h1) << 16);
    bar_lds();   // BAR2: h tile ready for next step (out store stays in flight)
  }
}

// ---------------- FC: one wave per (b,t), bf16 input rows ----------------
__global__ __launch_bounds__(64) void fc_kernel(const u16* __restrict__ out1,
                                                const float* __restrict__ fcw,
                                                const float* __restrict__ fcb,
                                                float* __restrict__ feats) {
  const int bs = blockIdx.x;
  const int l = threadIdx.x;
  const u16* row = out1 + (size_t)bs * HIDn;
  uint4 rv = *reinterpret_cast<const uint4*>(row + l * 8);
  float v[8];
  v[0] = bflo(rv.x); v[1] = bfhi(rv.x);
  v[2] = bflo(rv.y); v[3] = bfhi(rv.y);
  v[4] = bflo(rv.z); v[5] = bfhi(rv.z);
  v[6] = bflo(rv.w); v[7] = bfhi(rv.w);
#pragma unroll
  for (int tag = 0; tag < Tn; ++tag) {
    const float* w = fcw + tag * HIDn + l * 8;
    float4 w0 = *reinterpret_cast<const float4*>(w);
    float4 w1 = *reinterpret_cast<const float4*>(w + 4);
    float acc = v[0] * w0.x + v[1] * w0.y + v[2] * w0.z + v[3] * w0.w
              + v[4] * w1.x + v[5] * w1.y + v[6] * w1.z + v[7] * w1.w;
#pragma unroll
    for (int off = 32; off; off >>= 1) acc += __shfl_xor(acc, off);
    if (l == 0) feats[bs * Tn + tag] = acc + fcb[tag];
  }
}

// ---------------- CRF forward + gold, one wave per batch ----------------
__global__ __launch_bounds__(64) void crf_kernel(const float* __restrict__ feats,
                                                 const int* __restrict__ tags,
                                                 const int* __restrict__ lens,
                                                 const float* __restrict__ trans,
                                                 float* __restrict__ scores) {
  const int b = blockIdx.x;
  const int j = threadIdx.x;
  const int jj = j < Tn ? j : Tn - 1;
  const int len = lens[b];

  float trc[Tn];
#pragma unroll
  for (int i = 0; i < Tn; ++i) trc[i] = trans[i * Tn + jj];
  const float trS = trans[jj * Tn + STOP_T];

  float alpha = (j == START_T) ? 0.0f : NEGV;
  const float* fb = feats + (size_t)b * Sn * Tn;

  for (int t = 0; t < Sn; ++t) {
    float f = (j < Tn) ? fb[t * Tn + j] : 0.0f;
    float v[Tn];
    float m = -3.0e38f;
#pragma unroll
    for (int i = 0; i < Tn; ++i) {
      float ai = __shfl(alpha, i);
      v[i] = ai + trc[i];
      m = fmaxf(m, v[i]);
    }
    float ssum = 0.0f;
#pragma unroll
    for (int i = 0; i < Tn; ++i) ssum += __expf(v[i] - m);
    float newa = m + __logf(ssum) + f;
    if (t < len && j < Tn) alpha = newa;
  }

  float val = (j < Tn) ? alpha + trS : -3.0e38f;
  float m = val;
#pragma unroll
  for (int off = 32; off; off >>= 1) m = fmaxf(m, __shfl_xor(m, off));
  float se = (j < Tn) ? __expf(val - m) : 0.0f;
#pragma unroll
  for (int off = 32; off; off >>= 1) se += __shfl_xor(se, off);
  float fscore = m + __logf(se);

  const int* tg = tags + b * Sn;
  float part = 0.0f;
  for (int q = 0; q < 8; ++q) {
    int s0 = j * 8 + q;
    if (s0 < Sn - 1 && (s0 + 1) < len) {
      int ta = tg[s0], tb = tg[s0 + 1];
      part += trans[ta * Tn + tb] + fb[s0 * Tn + tb];
    }
  }
#pragma unroll
  for (int off = 32; off; off >>= 1) part += __shfl_xor(part, off);

  if (j == 0) {
    int t0 = tg[0];
    int tl = tg[len - 1];
    float gold = trans[START_T * Tn + t0] + fb[0 * Tn + t0] + part + trans[tl * Tn + STOP_T];
    scores[b] = fscore - gold;
  }
}

__global__ void finalize_kernel(const float* __restrict__ scores, float* __restrict__ out) {
  int l = threadIdx.x;
  float v = scores[l];
#pragma unroll
  for (int off = 32; off; off >>= 1) v += __shfl_xor(v, off);
  if (l == 0) out[0] = v / 64.0f;
}

extern "C" void kernel_launch(void* const* d_in, const int* in_sizes, int n_in,
                              void* d_out, int out_size, void* d_ws, size_t ws_size,
                              hipStream_t stream) {
  const int* sent = (const int*)d_in[0];
  const int* tags = (const int*)d_in[1];
  const int* lens = (const int*)d_in[2];
  const float* emb = (const float*)d_in[3];
  const float* wih0 = (const float*)d_in[4];
  const float* whh0 = (const float*)d_in[5];
  const float* bih0 = (const float*)d_in[6];
  const float* bhh0 = (const float*)d_in[7];
  const float* wih1 = (const float*)d_in[8];
  const float* whh1 = (const float*)d_in[9];
  const float* bih1 = (const float*)d_in[10];
  const float* bhh1 = (const float*)d_in[11];
  const float* fcw = (const float*)d_in[12];
  const float* fcb = (const float*)d_in[13];
  const float* trans = (const float*)d_in[14];

  // workspace (~172 MB)
  char* ws = (char*)d_ws;
  u16* outb = (u16*)ws;                                  // 33,554,432 B
  u16* gx2 = (u16*)(ws + 33554432);                      // 134,217,728 B
  float* feats = (float*)gx2;                            // aliases gx2 (dead before fc)
  char* p = ws + 33554432 + 134217728;
  float* scores = (float*)p;            p += 256;
  float* bias0 = (float*)p;             p += 8192;
  float* bias1 = (float*)p;             p += 8192;
  u16* wifrag0 = (u16*)p;               p += 1048576;    // 524,288 u16
  u16* wifrag1 = (u16*)p;               p += 2097152;    // 1,048,576 u16
  char* wq0 = p;                        p += 524288;     // int8 whh frags layer0
  char* wq1 = p;                        p += 524288;     // int8 whh frags layer1
  float* sw0 = (float*)p;               p += 8192;
  float* dqs0 = (float*)p;              p += 8192;
  float* sw1 = (float*)p;               p += 8192;
  float* dqs1 = (float*)p;              p += 8192;

  prep_scales<<<8, 256, 0, stream>>>(whh0, whh1, sw0, dqs0, sw1, dqs1);
  prep_kernel<<<2048, 256, 0, stream>>>(wih0, whh0, bih0, bhh0, wih1, whh1, bih1, bhh1,
                                        wifrag0, wifrag1, wq0, wq1, sw0, sw1, bias0, bias1);

  dim3 ggrid(Mn / 64, 2);
  gemm_ih<8, true><<<ggrid, 256, 0, stream>>>(emb, sent, (const uint4*)wifrag0, bias0, gx2);
  lstm_recur_v11<<<32, 512, 0, stream>>>((const i32x4*)wq0, dqs0, gx2, outb);
  gemm_ih<16, false><<<ggrid, 256, 0, stream>>>(outb, nullptr, (const uint4*)wifrag1, bias1, gx2);
  lstm_recur_v11<<<32, 512, 0, stream>>>((const i32x4*)wq1, dqs1, gx2, outb);

  fc_kernel<<<Mn, 64, 0, stream>>>(outb, fcw, fcb, feats);
  crf_kernel<<<Bn, 64, 0, stream>>>(feats, tags, lens, trans, scores);
  finalize_kernel<<<1, 64, 0, stream>>>(scores, (float*)d_out);
}

// Round 7
// 1795.217 us; speedup vs baseline: 1.3776x; 1.3776x over previous
//
#include <hip/hip_runtime.h>
#include <math.h>

#define NEGV (-100000.0f)
constexpr int Bn = 64, Sn = 512, En = 256, Hn = 256, HIDn = 512, Tn = 9;
constexpr int START_T = Tn - 2, STOP_T = Tn - 1;
constexpr int Mn = Bn * Sn; // 32768 rows

typedef unsigned int u32;
typedef unsigned short u16;
typedef unsigned long long u64;
typedef short short8 __attribute__((ext_vector_type(8)));
typedef float f32x4 __attribute__((ext_vector_type(4)));
typedef int i32x4 __attribute__((ext_vector_type(4)));

__device__ __forceinline__ float sigf(float x) { return 1.0f / (1.0f + __expf(-x)); }
__device__ __forceinline__ float tanh_f(float x) { return 2.0f / (1.0f + __expf(-2.0f * x)) - 1.0f; }
__device__ __forceinline__ u16 f2bf(float f) {
  u32 u = __float_as_uint(f);
  return (u16)((u + 0x7fffu + ((u >> 16) & 1u)) >> 16);
}
__device__ __forceinline__ float bflo(u32 u) { return __uint_as_float(u << 16); }
__device__ __forceinline__ float bfhi(u32 u) { return __uint_as_float(u & 0xffff0000u); }
__device__ __forceinline__ float b2f(u16 v) { return __uint_as_float((u32)v << 16); }

// LDS-only workgroup barrier: does NOT drain vmcnt (global loads/stores stay in flight).
__device__ __forceinline__ void bar_lds() {
  __builtin_amdgcn_sched_barrier(0);
  asm volatile("s_waitcnt lgkmcnt(0)" ::: "memory");
  __builtin_amdgcn_s_barrier();
  __builtin_amdgcn_sched_barrier(0);
}

// ---------------- scales for int8 recurrent weights: per gate-row ----------------
__global__ void prep_scales(const float* __restrict__ whh0, const float* __restrict__ whh1,
                            float* __restrict__ sw0, float* __restrict__ dqs0,
                            float* __restrict__ sw1, float* __restrict__ dqs1) {
  int r = blockIdx.x * blockDim.x + threadIdx.x;
  if (r >= 2048) return;
  const float* p0 = whh0 + (size_t)r * 256;
  const float* p1 = whh1 + (size_t)r * 256;
  float m0 = 0.f, m1 = 0.f;
  for (int k = 0; k < 256; ++k) {
    m0 = fmaxf(m0, fabsf(p0[k]));
    m1 = fmaxf(m1, fabsf(p1[k]));
  }
  m0 = fmaxf(m0, 1e-8f); m1 = fmaxf(m1, 1e-8f);
  sw0[r] = m0 / 127.f; dqs0[r] = m0 / (127.f * 127.f);
  sw1[r] = m1 / 127.f; dqs1[r] = m1 / (127.f * 127.f);
}

// ---------------- prep: wih -> bf16 MFMA B-frags; whh -> int8 MFMA B-frags ----------------
// whh i8 frags: wq[d][w(8)][q(8)][kt(4)][lane(64)][j(16)];
//   n=(q*8+w)*16+(lane&15); k=kt*64+((lane>>4)&3)*16+j
// wih frags (gemm): wifrag[d][nb][w][ks][lane][j]; n=nb*64+w*16+(lane&15); k=ks*32+((lane>>4)&3)*8+j
__global__ void prep_kernel(const float* __restrict__ wih0, const float* __restrict__ whh0,
                            const float* __restrict__ bih0, const float* __restrict__ bhh0,
                            const float* __restrict__ wih1, const float* __restrict__ whh1,
                            const float* __restrict__ bih1, const float* __restrict__ bhh1,
                            u16* __restrict__ wifrag0, u16* __restrict__ wifrag1,
                            char* __restrict__ wq0, char* __restrict__ wq1,
                            const float* __restrict__ sw0, const float* __restrict__ sw1,
                            float* __restrict__ bias0, float* __restrict__ bias1) {
  int tid = blockIdx.x * blockDim.x + threadIdx.x;
  int nth = gridDim.x * blockDim.x;
  // wih0 frags: K=256, KS=8 -> 2*16*4*8*64*8 = 524288 u16
  for (int idx = tid; idx < 524288; idx += nth) {
    int j = idx & 7, lane = (idx >> 3) & 63, ks = (idx >> 9) & 7,
        w2 = (idx >> 12) & 3, nb = (idx >> 14) & 15, d = (idx >> 18) & 1;
    int n = nb * 64 + w2 * 16 + (lane & 15);
    int k = ks * 32 + ((lane >> 4) & 3) * 8 + j;
    wifrag0[idx] = f2bf(wih0[(d * 1024 + n) * 256 + k]);
  }
  // wih1 frags: K=512, KS=16 -> 2*16*4*16*64*8 = 1048576 u16
  for (int idx = tid; idx < 1048576; idx += nth) {
    int j = idx & 7, lane = (idx >> 3) & 63, ks = (idx >> 9) & 15,
        w2 = (idx >> 13) & 3, nb = (idx >> 15) & 15, d = (idx >> 19) & 1;
    int n = nb * 64 + w2 * 16 + (lane & 15);
    int k = ks * 32 + ((lane >> 4) & 3) * 8 + j;
    wifrag1[idx] = f2bf(wih1[(d * 1024 + n) * 512 + k]);
  }
  // whh int8 frags: [d][w][q][kt][lane][j] -> 524288 bytes per layer
  for (int idx = tid; idx < 524288; idx += nth) {
    int j = idx & 15, lane = (idx >> 4) & 63, kt = (idx >> 10) & 3,
        q = (idx >> 12) & 7, wv = (idx >> 15) & 7, d = (idx >> 18) & 1;
    int nt = q * 8 + wv;
    int n = nt * 16 + (lane & 15);
    int k = kt * 64 + ((lane >> 4) & 3) * 16 + j;
    int row = d * 1024 + n;
    float v0 = whh0[(size_t)row * 256 + k] / sw0[row];
    float v1 = whh1[(size_t)row * 256 + k] / sw1[row];
    wq0[idx] = (char)(int)fminf(fmaxf(rintf(v0), -127.f), 127.f);
    wq1[idx] = (char)(int)fminf(fmaxf(rintf(v1), -127.f), 127.f);
  }
  for (int idx = tid; idx < 2 * 1024; idx += nth) {
    bias0[idx] = bih0[idx] + bhh0[idx];
    bias1[idx] = bih1[idx] + bhh1[idx];
  }
}

// ---------------- MFMA input-projection GEMM -> gate-packed gx2[dir][m][unit][gate] ----------------
template <int KS, bool GATHER>   // KS = K/32
__global__ __launch_bounds__(256) void gemm_ih(
    const void* __restrict__ xsrc_v,   // GATHER: fp32 emb; else bf16 rows [M][512]
    const int* __restrict__ sent,
    const uint4* __restrict__ wifrag,  // [2][16][4][KS][64] uint4
    const float* __restrict__ bias,    // [2][1024]
    u16* __restrict__ gx2)             // [2*M][256][4] bf16
{
  constexpr int K = KS * 32;
  constexpr int PITCH = K + 8;
  __shared__ u16 As[64][PITCH];
  const int tid = threadIdx.x;
  const int l = tid & 63;
  const int w = tid >> 6;
  const int col = l & 15;
  const int quad = (l >> 4) & 3;
  const int m0 = blockIdx.x * 64;
  const int dir = blockIdx.y;

  {
    const int lr = tid >> 2, lq = tid & 3;
    if constexpr (GATHER) {
      const float4* xrow = reinterpret_cast<const float4*>(
          (const float*)xsrc_v + (size_t)sent[m0 + lr] * 256) + lq * 16;
      u32* dst = reinterpret_cast<u32*>(&As[lr][lq * 64]);
#pragma unroll
      for (int i = 0; i < 16; ++i) {
        float4 v = xrow[i];
        dst[i * 2 + 0] = (u32)f2bf(v.x) | ((u32)f2bf(v.y) << 16);
        dst[i * 2 + 1] = (u32)f2bf(v.z) | ((u32)f2bf(v.w) << 16);
      }
    } else {
      const uint4* xrow = reinterpret_cast<const uint4*>(
          (const u16*)xsrc_v + (size_t)(m0 + lr) * 512) + lq * 16;
      uint4* dst = reinterpret_cast<uint4*>(&As[lr][lq * 128]);
#pragma unroll
      for (int i = 0; i < 16; ++i) dst[i] = xrow[i];
    }
  }
  __syncthreads();

  const uint4* wfd = wifrag + (size_t)dir * 16 * 4 * KS * 64;
#pragma unroll 1
  for (int nb = 0; nb < 16; ++nb) {
    uint4 bf[KS];
#pragma unroll
    for (int ks = 0; ks < KS; ++ks)
      bf[ks] = wfd[((nb * 4 + w) * KS + ks) * 64 + l];

    f32x4 acc[4];
#pragma unroll
    for (int mt = 0; mt < 4; ++mt) acc[mt] = (f32x4){0.f, 0.f, 0.f, 0.f};
#pragma unroll
    for (int ks = 0; ks < KS; ++ks) {
      short8 b8 = __builtin_bit_cast(short8, bf[ks]);
#pragma unroll
      for (int mt = 0; mt < 4; ++mt) {
        uint4 av = *reinterpret_cast<const uint4*>(&As[mt * 16 + col][ks * 32 + quad * 8]);
        acc[mt] = __builtin_amdgcn_mfma_f32_16x16x32_bf16(
            __builtin_bit_cast(short8, av), b8, acc[mt], 0, 0, 0);
      }
    }

    const int n = nb * 64 + w * 16 + col;
    const int gate = n >> 8, unit = n & 255;
    const float bv = bias[dir * 1024 + n];
#pragma unroll
    for (int mt = 0; mt < 4; ++mt) {
#pragma unroll
      for (int r = 0; r < 4; ++r) {
        int m = m0 + mt * 16 + quad * 4 + r;
        gx2[((size_t)(dir * Mn + m) * 256 + unit) * 4 + gate] = f2bf(acc[mt][r] + bv);
      }
    }
  }
}

// ---------------- MFMA recurrence v12: 2-row blocks, wave-local acc handoff, 1 barrier/step ----
// Grid: 64 blocks = (dir 2) x (2-row group 32). Block: 512 thr = 8 waves, 2 waves/SIMD.
// Wave w holds n-tiles q*8+w (q=0..7) of Whh in registers (bw[8][4] i32x4 = 128 regs);
// wave w owns units {e*128 + w*16 + c}. Per step:
//   ds_read A (rows repeat mod 2) -> 32 MFMA -> quad0 scatter raw i32 acc to PER-WAVE LDS slab
//   -> lgkmcnt (wave-local, NO barrier) -> each lane: 1 (unit,row) task: dequant+nonlin
//   -> h to Ah8[wb] (int8) + out (bf16) -> ONE lgkm-only barrier.
__global__ __launch_bounds__(512, 2) void lstm_recur_v12(
    const i32x4* __restrict__ wq,     // [2][8][8][4][64] i32x4
    const float* __restrict__ dqs,    // [2][1024]
    const u16* __restrict__ gx2,      // [2*Mn][256][4] bf16
    u16* __restrict__ out)            // [B][S][512] bf16
{
  __shared__ char Ah8[2][2][288];     // dbuf int8 h tile [2 rows][256 units], padded pitch
  __shared__ int accW[8][2][32][4];   // per-wave raw i32 acc [wave][row][unit-idx][gate]
  const int tid = threadIdx.x;
  const int l = tid & 63;
  const int w = tid >> 6;             // wave 0..7
  const int col = l & 15;
  const int quad = (l >> 4) & 3;
  const int dir = blockIdx.x >> 5;
  const int bq = blockIdx.x & 31;

  // ---- int8 recurrent weights into registers: 32 x i32x4 per lane ----
  i32x4 bw[8][4];
  {
    const i32x4* wp = wq + ((size_t)dir * 8 + w) * 8 * 4 * 64;
#pragma unroll
    for (int q = 0; q < 8; ++q)
#pragma unroll
      for (int kt = 0; kt < 4; ++kt)
        bw[q][kt] = wp[(q * 4 + kt) * 64 + l];
  }

  // epilogue task for this lane: row r_ep (0..1), unit-idx ue (0..31) within wave w
  const int r_ep = l >> 5;
  const int ue = l & 31;
  const int e_ep = ue >> 4, c_ep = ue & 15;
  const int unit = e_ep * 128 + w * 16 + c_ep;

  float sc[4];
#pragma unroll
  for (int g = 0; g < 4; ++g)
    sc[g] = dqs[dir * 1024 + g * 256 + unit];

  const int mrow = bq * 2 + r_ep;
  const uint2* gp = reinterpret_cast<const uint2*>(gx2) +
                    (size_t)(dir * Mn + mrow * Sn) * 256 + unit;
  u16* op = out + (size_t)mrow * Sn * HIDn + dir * Hn + unit;

  float c_st = 0.f;

  for (int s = 0; s < Sn; ++s) {
    const int t = dir ? (Sn - 1 - s) : s;
    uint2 g2 = gp[(size_t)t * 256];   // 4 gate bf16 for (mrow, t, unit); in flight across phases

    if (s > 0) {
      const int rb = (s + 1) & 1;
      i32x4 av[4];
#pragma unroll
      for (int kt = 0; kt < 4; ++kt)
        av[kt] = *reinterpret_cast<const i32x4*>(
            &Ah8[rb][col & 1][kt * 64 + quad * 16]);
      i32x4 acc[8];
#pragma unroll
      for (int q = 0; q < 8; ++q) acc[q] = (i32x4){0, 0, 0, 0};
#pragma unroll
      for (int kt = 0; kt < 4; ++kt)
#pragma unroll
        for (int q = 0; q < 8; ++q)
          acc[q] = __builtin_amdgcn_mfma_i32_16x16x64_i8(av[kt], bw[q][kt], acc[q], 0, 0, 0);
      // wave-local scatter: quad0 lanes hold C rows 0..3; rows 0,1 are the real batch rows
      if (quad == 0) {
#pragma unroll
        for (int e = 0; e < 2; ++e)
#pragma unroll
          for (int r = 0; r < 2; ++r) {
            i32x4 v = (i32x4){acc[0 + e][r], acc[2 + e][r], acc[4 + e][r], acc[6 + e][r]};
            *reinterpret_cast<i32x4*>(&accW[w][r][e * 16 + col][0]) = v;
          }
      }
      // no barrier: same-wave LDS RAW ordered by lgkmcnt (compiler-inserted)
    }

    float a0 = 0.f, a1 = 0.f, a2 = 0.f, a3 = 0.f;
    if (s > 0) {
      i32x4 q0 = *reinterpret_cast<const i32x4*>(&accW[w][r_ep][ue][0]);
      a0 = (float)q0[0] * sc[0];
      a1 = (float)q0[1] * sc[1];
      a2 = (float)q0[2] * sc[2];
      a3 = (float)q0[3] * sc[3];
    }
    float gi_ = a0 + b2f((u16)(g2.x & 0xffff));
    float gf_ = a1 + b2f((u16)(g2.x >> 16));
    float gg_ = a2 + b2f((u16)(g2.y & 0xffff));
    float go_ = a3 + b2f((u16)(g2.y >> 16));

    c_st = sigf(gf_) * c_st + sigf(gi_) * tanh_f(gg_);
    float h = sigf(go_) * tanh_f(c_st);

    Ah8[s & 1][r_ep][unit] = (char)(int)rintf(h * 127.f);
    op[(size_t)t * HIDn] = f2bf(h);
    bar_lds();   // ONE barrier: h tile (wb) visible to all waves; out store stays in flight
  }
}

// ---------------- FC: one wave per (b,t), bf16 input rows ----------------
__global__ __launch_bounds__(64) void fc_kernel(const u16* __restrict__ out1,
                                                const float* __restrict__ fcw,
                                                const float* __restrict__ fcb,
                                                float* __restrict__ feats) {
  const int bs = blockIdx.x;
  const int l = threadIdx.x;
  const u16* row = out1 + (size_t)bs * HIDn;
  uint4 rv = *reinterpret_cast<const uint4*>(row + l * 8);
  float v[8];
  v[0] = bflo(rv.x); v[1] = bfhi(rv.x);
  v[2] = bflo(rv.y); v[3] = bfhi(rv.y);
  v[4] = bflo(rv.z); v[5] = bfhi(rv.z);
  v[6] = bflo(rv.w); v[7] = bfhi(rv.w);
#pragma unroll
  for (int tag = 0; tag < Tn; ++tag) {
    const float* w = fcw + tag * HIDn + l * 8;
    float4 w0 = *reinterpret_cast<const float4*>(w);
    float4 w1 = *reinterpret_cast<const float4*>(w + 4);
    float acc = v[0] * w0.x + v[1] * w0.y + v[2] * w0.z + v[3] * w0.w
              + v[4] * w1.x + v[5] * w1.y + v[6] * w1.z + v[7] * w1.w;
#pragma unroll
    for (int off = 32; off; off >>= 1) acc += __shfl_xor(acc, off);
    if (l == 0) feats[bs * Tn + tag] = acc + fcb[tag];
  }
}

// ---------------- CRF forward + gold, one wave per batch ----------------
__global__ __launch_bounds__(64) void crf_kernel(const float* __restrict__ feats,
                                                 const int* __restrict__ tags,
                                                 const int* __restrict__ lens,
                                                 const float* __restrict__ trans,
                                                 float* __restrict__ scores) {
  const int b = blockIdx.x;
  const int j = threadIdx.x;
  const int jj = j < Tn ? j : Tn - 1;
  const int len = lens[b];

  float trc[Tn];
#pragma unroll
  for (int i = 0; i < Tn; ++i) trc[i] = trans[i * Tn + jj];
  const float trS = trans[jj * Tn + STOP_T];

  float alpha = (j == START_T) ? 0.0f : NEGV;
  const float* fb = feats + (size_t)b * Sn * Tn;

  for (int t = 0; t < Sn; ++t) {
    float f = (j < Tn) ? fb[t * Tn + j] : 0.0f;
    float v[Tn];
    float m = -3.0e38f;
#pragma unroll
    for (int i = 0; i < Tn; ++i) {
      float ai = __shfl(alpha, i);
      v[i] = ai + trc[i];
      m = fmaxf(m, v[i]);
    }
    float ssum = 0.0f;
#pragma unroll
    for (int i = 0; i < Tn; ++i) ssum += __expf(v[i] - m);
    float newa = m + __logf(ssum) + f;
    if (t < len && j < Tn) alpha = newa;
  }

  float val = (j < Tn) ? alpha + trS : -3.0e38f;
  float m = val;
#pragma unroll
  for (int off = 32; off; off >>= 1) m = fmaxf(m, __shfl_xor(m, off));
  float se = (j < Tn) ? __expf(val - m) : 0.0f;
#pragma unroll
  for (int off = 32; off; off >>= 1) se += __shfl_xor(se, off);
  float fscore = m + __logf(se);

  const int* tg = tags + b * Sn;
  float part = 0.0f;
  for (int q = 0; q < 8; ++q) {
    int s0 = j * 8 + q;
    if (s0 < Sn - 1 && (s0 + 1) < len) {
      int ta = tg[s0], tb = tg[s0 + 1];
      part += trans[ta * Tn + tb] + fb[s0 * Tn + tb];
    }
  }
#pragma unroll
  for (int off = 32; off; off >>= 1) part += __shfl_xor(part, off);

  if (j == 0) {
    int t0 = tg[0];
    int tl = tg[len - 1];
    float gold = trans[START_T * Tn + t0] + fb[0 * Tn + t0] + part + trans[tl * Tn + STOP_T];
    scores[b] = fscore - gold;
  }
}

__global__ void finalize_kernel(const float* __restrict__ scores, float* __restrict__ out) {
  int l = threadIdx.x;
  float v = scores[l];
#pragma unroll
  for (int off = 32; off; off >>= 1) v += __shfl_xor(v, off);
  if (l == 0) out[0] = v / 64.0f;
}

extern "C" void kernel_launch(void* const* d_in, const int* in_sizes, int n_in,
                              void* d_out, int out_size, void* d_ws, size_t ws_size,
                              hipStream_t stream) {
  const int* sent = (const int*)d_in[0];
  const int* tags = (const int*)d_in[1];
  const int* lens = (const int*)d_in[2];
  const float* emb = (const float*)d_in[3];
  const float* wih0 = (const float*)d_in[4];
  const float* whh0 = (const float*)d_in[5];
  const float* bih0 = (const float*)d_in[6];
  const float* bhh0 = (const float*)d_in[7];
  const float* wih1 = (const float*)d_in[8];
  const float* whh1 = (const float*)d_in[9];
  const float* bih1 = (const float*)d_in[10];
  const float* bhh1 = (const float*)d_in[11];
  const float* fcw = (const float*)d_in[12];
  const float* fcb = (const float*)d_in[13];
  const float* trans = (const float*)d_in[14];

  // workspace (~172 MB)
  char* ws = (char*)d_ws;
  u16* outb = (u16*)ws;                                  // 33,554,432 B
  u16* gx2 = (u16*)(ws + 33554432);                      // 134,217,728 B
  float* feats = (float*)gx2;                            // aliases gx2 (dead before fc)
  char* p = ws + 33554432 + 134217728;
  float* scores = (float*)p;            p += 256;
  float* bias0 = (float*)p;             p += 8192;
  float* bias1 = (float*)p;             p += 8192;
  u16* wifrag0 = (u16*)p;               p += 1048576;    // 524,288 u16
  u16* wifrag1 = (u16*)p;               p += 2097152;    // 1,048,576 u16
  char* wq0 = p;                        p += 524288;     // int8 whh frags layer0
  char* wq1 = p;                        p += 524288;     // int8 whh frags layer1
  float* sw0 = (float*)p;               p += 8192;
  float* dqs0 = (float*)p;              p += 8192;
  float* sw1 = (float*)p;               p += 8192;
  float* dqs1 = (float*)p;              p += 8192;

  prep_scales<<<8, 256, 0, stream>>>(whh0, whh1, sw0, dqs0, sw1, dqs1);
  prep_kernel<<<2048, 256, 0, stream>>>(wih0, whh0, bih0, bhh0, wih1, whh1, bih1, bhh1,
                                        wifrag0, wifrag1, wq0, wq1, sw0, sw1, bias0, bias1);

  dim3 ggrid(Mn / 64, 2);
  gemm_ih<8, true><<<ggrid, 256, 0, stream>>>(emb, sent, (const uint4*)wifrag0, bias0, gx2);
  lstm_recur_v12<<<64, 512, 0, stream>>>((const i32x4*)wq0, dqs0, gx2, outb);
  gemm_ih<16, false><<<ggrid, 256, 0, stream>>>(outb, nullptr, (const uint4*)wifrag1, bias1, gx2);
  lstm_recur_v12<<<64, 512, 0, stream>>>((const i32x4*)wq1, dqs1, gx2, outb);

  fc_kernel<<<Mn, 64, 0, stream>>>(outb, fcw, fcb, feats);
  crf_kernel<<<Bn, 64, 0, stream>>>(feats, tags, lens, trans, scores);
  finalize_kernel<<<1, 64, 0, stream>>>(scores, (float*)d_out);
}